// Round 1
// baseline (283.593 us; speedup 1.0000x reference)
//
#include <hip/hip_runtime.h>
#include <hip/hip_bf16.h>

// GraphSAGE inference, MI355X. Pipeline:
//  1. transpose+cast weights f32 -> bf16 [N][K] (NT-GEMM form)
//  2. gather x rows -> bf16 (Hs, H0s); gather+mean -> bf16 (Hm, H0m)
//  3. layer-0 GEMMs (MFMA 16x16x32 bf16, 128x128 tile, relu, concat via col offset)
//  4. mean over 25 of C1 -> M1
//  5. layer-1 dual GEMM: out = C0@Ws1 + M1@Wn1 (f32 out)

#define DEVINL __device__ __forceinline__

typedef __bf16 bf16x8 __attribute__((ext_vector_type(8)));
typedef float f32x4 __attribute__((ext_vector_type(4)));

DEVINL unsigned short f2bf(float f) {
  union { float f; unsigned u; } v; v.f = f;
  unsigned r = v.u + 0x7FFFu + ((v.u >> 16) & 1u);  // RNE
  return (unsigned short)(r >> 16);
}
DEVINL float bf2f(unsigned short h) {
  union { unsigned u; float f; } v; v.u = ((unsigned)h) << 16;
  return v.f;
}

DEVINL void gload_lds16(const void* g, void* l) {
  __builtin_amdgcn_global_load_lds(
      (const __attribute__((address_space(1))) void*)g,
      (__attribute__((address_space(3))) void*)l, 16, 0, 0);
}

// ---- WT[n*K+k] = bf16(W[k*N+n])
__global__ void transpose_cast_kernel(const float* __restrict__ W,
                                      unsigned short* __restrict__ WT,
                                      int K, int N) {
  int t = blockIdx.x * blockDim.x + threadIdx.x;
  if (t >= K * N) return;
  int k = t % K, n = t / K;
  WT[t] = f2bf(W[(size_t)k * N + n]);
}

// ---- out[row] = bf16(x[idx[row]]), rows of 512 f32. 256 thr = 2 rows/block.
__global__ void gather_cast_kernel(const float* __restrict__ x,
                                   const int* __restrict__ idx,
                                   unsigned short* __restrict__ out,
                                   int nrows) {
  int row = blockIdx.x * 2 + (threadIdx.x >> 7);
  if (row >= nrows) return;
  int c4 = (threadIdx.x & 127) << 2;
  const float4 v = *reinterpret_cast<const float4*>(x + (size_t)idx[row] * 512 + c4);
  ushort4 o; o.x = f2bf(v.x); o.y = f2bf(v.y); o.z = f2bf(v.z); o.w = f2bf(v.w);
  *reinterpret_cast<ushort4*>(out + (size_t)row * 512 + c4) = o;
}

// ---- out[row] = bf16(mean_{j<FAN} x[idx[row*FAN+j]])
template <int FAN>
__global__ void gather_mean_kernel(const float* __restrict__ x,
                                   const int* __restrict__ idx,
                                   unsigned short* __restrict__ out,
                                   int nrows) {
  int row = blockIdx.x * 2 + (threadIdx.x >> 7);
  if (row >= nrows) return;
  int c4 = (threadIdx.x & 127) << 2;
  float4 acc = {0.f, 0.f, 0.f, 0.f};
  const int* ip = idx + (size_t)row * FAN;
  for (int j = 0; j < FAN; ++j) {
    const float4 v = *reinterpret_cast<const float4*>(x + (size_t)ip[j] * 512 + c4);
    acc.x += v.x; acc.y += v.y; acc.z += v.z; acc.w += v.w;
  }
  const float s = 1.0f / FAN;
  ushort4 o; o.x = f2bf(acc.x * s); o.y = f2bf(acc.y * s);
  o.z = f2bf(acc.z * s); o.w = f2bf(acc.w * s);
  *reinterpret_cast<ushort4*>(out + (size_t)row * 512 + c4) = o;
}

// ---- M1[b] = bf16(mean_{j<25} C1[b*25+j]), 1024 cols bf16. 1 row/block, 256 thr.
__global__ void mean25_bf16_kernel(const unsigned short* __restrict__ in,
                                   unsigned short* __restrict__ out) {
  int b = blockIdx.x;
  int c4 = threadIdx.x << 2;
  float a0 = 0, a1 = 0, a2 = 0, a3 = 0;
  for (int j = 0; j < 25; ++j) {
    ushort4 v = *reinterpret_cast<const ushort4*>(in + ((size_t)(b * 25 + j)) * 1024 + c4);
    a0 += bf2f(v.x); a1 += bf2f(v.y); a2 += bf2f(v.z); a3 += bf2f(v.w);
  }
  const float s = 1.0f / 25.0f;
  ushort4 o; o.x = f2bf(a0 * s); o.y = f2bf(a1 * s); o.z = f2bf(a2 * s); o.w = f2bf(a3 * s);
  *reinterpret_cast<ushort4*>(out + (size_t)b * 1024 + c4) = o;
}

// ---- NT GEMM: C[M,N](+col0, ld=ldc) = op(A[M,K] @ Bt[N,K]^T), bf16 in, MFMA.
// 128x128 tile, BK=32, 256 thr = 4 waves (2x2), wave tile 64x64 (4x4 frags).
// DUAL: second pass accumulates A2 @ Bt2^T (same K).
// Requires M%128==0, N%128==0, K%32==0.
template <bool RELU, bool OUTF32, bool DUAL>
__global__ __launch_bounds__(256) void gemm_nt_kernel(
    const unsigned short* __restrict__ A,
    const unsigned short* __restrict__ Bt,
    const unsigned short* __restrict__ A2,
    const unsigned short* __restrict__ Bt2,
    void* __restrict__ C, int K, int ldc, int col0) {
  __shared__ __align__(16) unsigned short As[128 * 32];
  __shared__ __align__(16) unsigned short Bs[128 * 32];
  const int t = threadIdx.x;
  const int w = t >> 6;
  const int l = t & 63;
  const int wm = w >> 1, wn = w & 1;
  const long tm = (long)blockIdx.y * 128;
  const long tn = (long)blockIdx.x * 128;

  f32x4 acc[4][4] = {};

  // staging: per round, each wave stages 16 rows (1024 B) of the [128][32] tile.
  // HW writes LDS at wave-uniform base + lane*16 B; lane l covers row l>>2,
  // k-chunk (l&3)*8 elems.
  const int s_r = l >> 2;
  const int s_kc = (l & 3) * 8;

  const int npass = DUAL ? 2 : 1;
  for (int pass = 0; pass < npass; ++pass) {
    const unsigned short* pA = (DUAL && pass) ? A2 : A;
    const unsigned short* pB = (DUAL && pass) ? Bt2 : Bt;
    for (int kt = 0; kt < K; kt += 32) {
      __syncthreads();  // LDS free (prev compute done)
      #pragma unroll
      for (int r = 0; r < 2; ++r) {
        const int chunk = r * 64 + w * 16;  // row base of this wave's 1KB chunk
        gload_lds16(pA + (size_t)(tm + chunk + s_r) * K + kt + s_kc, As + chunk * 32);
        gload_lds16(pB + (size_t)(tn + chunk + s_r) * K + kt + s_kc, Bs + chunk * 32);
      }
      __syncthreads();  // staged (barrier drains vmcnt)

      bf16x8 af[4], bfr[4];
      const unsigned short* Ab = As + ((size_t)(wm * 64 + (l & 15)) * 32 + (l >> 4) * 8);
      const unsigned short* Bb = Bs + ((size_t)(wn * 64 + (l & 15)) * 32 + (l >> 4) * 8);
      #pragma unroll
      for (int f = 0; f < 4; ++f) {
        af[f] = *reinterpret_cast<const bf16x8*>(Ab + f * 16 * 32);
        bfr[f] = *reinterpret_cast<const bf16x8*>(Bb + f * 16 * 32);
      }
      #pragma unroll
      for (int i = 0; i < 4; ++i)
        #pragma unroll
        for (int j = 0; j < 4; ++j)
          acc[i][j] = __builtin_amdgcn_mfma_f32_16x16x32_bf16(af[i], bfr[j], acc[i][j], 0, 0, 0);
    }
  }

  // epilogue: C/D layout col = l&15, row = (l>>4)*4 + r  [m89/m91 verified]
  #pragma unroll
  for (int i = 0; i < 4; ++i) {
    #pragma unroll
    for (int j = 0; j < 4; ++j) {
      #pragma unroll
      for (int r = 0; r < 4; ++r) {
        float v = acc[i][j][r];
        if (RELU) v = fmaxf(v, 0.0f);
        const long row = tm + wm * 64 + i * 16 + (l >> 4) * 4 + r;
        const long col = col0 + tn + wn * 64 + j * 16 + (l & 15);
        if (OUTF32) ((float*)C)[row * ldc + col] = v;
        else        ((unsigned short*)C)[row * ldc + col] = f2bf(v);
      }
    }
  }
}

extern "C" void kernel_launch(void* const* d_in, const int* in_sizes, int n_in,
                              void* d_out, int out_size, void* d_ws, size_t ws_size,
                              hipStream_t stream) {
  const float* x      = (const float*)d_in[0];   // [200000, 512]
  const int*   nodes  = (const int*)d_in[1];     // [1024]
  const int*   neigh1 = (const int*)d_in[2];     // [25600]
  const int*   neigh2 = (const int*)d_in[3];     // [256000]
  const float* Ws0    = (const float*)d_in[4];   // [512, 512]
  const float* Wn0    = (const float*)d_in[5];   // [512, 512]
  const float* Ws1    = (const float*)d_in[6];   // [1024, 256]
  const float* Wn1    = (const float*)d_in[7];   // [1024, 256]
  float* out = (float*)d_out;                    // [1024, 256]

  // workspace layout (bf16 buffers), total ~107.5 MiB
  char* p = (char*)d_ws;
  unsigned short* WT0s = (unsigned short*)p; p += (size_t)512 * 512 * 2;
  unsigned short* WT0n = (unsigned short*)p; p += (size_t)512 * 512 * 2;
  unsigned short* WT1s = (unsigned short*)p; p += (size_t)256 * 1024 * 2;
  unsigned short* WT1n = (unsigned short*)p; p += (size_t)256 * 1024 * 2;
  unsigned short* H0s  = (unsigned short*)p; p += (size_t)1024 * 512 * 2;
  unsigned short* H0m  = (unsigned short*)p; p += (size_t)1024 * 512 * 2;
  unsigned short* Hs   = (unsigned short*)p; p += (size_t)25600 * 512 * 2;
  unsigned short* Hm   = (unsigned short*)p; p += (size_t)25600 * 512 * 2;
  unsigned short* C0   = (unsigned short*)p; p += (size_t)1024 * 1024 * 2;
  unsigned short* M1   = (unsigned short*)p; p += (size_t)1024 * 1024 * 2;
  unsigned short* C1   = (unsigned short*)p; p += (size_t)25600 * 1024 * 2;

  // 1. weights -> bf16, transposed to [N][K]
  hipLaunchKernelGGL(transpose_cast_kernel, dim3(1024), dim3(256), 0, stream, Ws0, WT0s, 512, 512);
  hipLaunchKernelGGL(transpose_cast_kernel, dim3(1024), dim3(256), 0, stream, Wn0, WT0n, 512, 512);
  hipLaunchKernelGGL(transpose_cast_kernel, dim3(1024), dim3(256), 0, stream, Ws1, WT1s, 1024, 256);
  hipLaunchKernelGGL(transpose_cast_kernel, dim3(1024), dim3(256), 0, stream, Wn1, WT1n, 1024, 256);

  // 2. gathers / means
  hipLaunchKernelGGL(gather_cast_kernel, dim3(12800), dim3(256), 0, stream, x, neigh1, Hs, 25600);
  hipLaunchKernelGGL(gather_cast_kernel, dim3(512), dim3(256), 0, stream, x, nodes, H0s, 1024);
  hipLaunchKernelGGL(gather_mean_kernel<10>, dim3(12800), dim3(256), 0, stream, x, neigh2, Hm, 25600);
  hipLaunchKernelGGL(gather_mean_kernel<25>, dim3(512), dim3(256), 0, stream, x, neigh1, H0m, 1024);

  // 3. layer 0: C1 = relu([Hs@Ws0 | Hm@Wn0]), C0 = relu([H0s@Ws0 | H0m@Wn0])
  hipLaunchKernelGGL((gemm_nt_kernel<true, false, false>), dim3(4, 200), dim3(256), 0, stream,
                     Hs, WT0s, Hs, WT0s, C1, 512, 1024, 0);
  hipLaunchKernelGGL((gemm_nt_kernel<true, false, false>), dim3(4, 200), dim3(256), 0, stream,
                     Hm, WT0n, Hm, WT0n, C1, 512, 1024, 512);
  hipLaunchKernelGGL((gemm_nt_kernel<true, false, false>), dim3(4, 8), dim3(256), 0, stream,
                     H0s, WT0s, H0s, WT0s, C0, 512, 1024, 0);
  hipLaunchKernelGGL((gemm_nt_kernel<true, false, false>), dim3(4, 8), dim3(256), 0, stream,
                     H0m, WT0n, H0m, WT0n, C0, 512, 1024, 512);

  // 4. M1 = mean25(C1)
  hipLaunchKernelGGL(mean25_bf16_kernel, dim3(1024), dim3(256), 0, stream, C1, M1);

  // 5. out = C0@Ws1 + M1@Wn1  (f32 out, no relu)
  hipLaunchKernelGGL((gemm_nt_kernel<false, true, true>), dim3(2, 8), dim3(256), 0, stream,
                     C0, WT1s, M1, WT1n, out, 1024, 256, 0);
}

// Round 2
// 190.931 us; speedup vs baseline: 1.4853x; 1.4853x over previous
//
#include <hip/hip_runtime.h>
#include <hip/hip_bf16.h>

// GraphSAGE inference, MI355X. R2: fused-row layout, 8 launches.
//  Hall  [26624][512] bf16 : rows 0-25599 = x[neigh1], 25600+ = x[nodes]
//  Hmall [26624][512] bf16 : rows 0-25599 = mean10(x[neigh2]), 25600+ = mean25(Hall rows)
//  C1all [26624][1024] bf16 = relu([Hall@Ws0 | Hmall@Wn0])   (rows 25600+ = C0)
//  M1    [1024][1024] bf16 = mean25(C1all rows 0-25599)
//  out   [1024][256] f32  = C0@Ws1 + M1@Wn1  (split-K atomic)

#define DEVINL __device__ __forceinline__

typedef __bf16 bf16x8 __attribute__((ext_vector_type(8)));
typedef float f32x4 __attribute__((ext_vector_type(4)));

DEVINL unsigned short f2bf(float f) {
  union { float f; unsigned u; } v; v.f = f;
  unsigned r = v.u + 0x7FFFu + ((v.u >> 16) & 1u);  // RNE
  return (unsigned short)(r >> 16);
}
DEVINL float bf2f(unsigned short h) {
  union { unsigned u; float f; } v; v.u = ((unsigned)h) << 16;
  return v.f;
}

DEVINL void gload_lds16(const void* g, void* l) {
  __builtin_amdgcn_global_load_lds(
      (const __attribute__((address_space(1))) void*)g,
      (__attribute__((address_space(3))) void*)l, 16, 0, 0);
}

// ---- all 4 weights -> bf16 [N][K] in one launch. regions of 262144 elems each.
__global__ void weights_cast_kernel(const float* __restrict__ Ws0, const float* __restrict__ Wn0,
                                    const float* __restrict__ Ws1, const float* __restrict__ Wn1,
                                    unsigned short* __restrict__ WT0s, unsigned short* __restrict__ WT0n,
                                    unsigned short* __restrict__ WT1s, unsigned short* __restrict__ WT1n) {
  int t = blockIdx.x * 256 + threadIdx.x;
  int region = t >> 18, local = t & 262143;
  const float* W; unsigned short* WT; int k, n, N;
  if (region == 0)      { W = Ws0; WT = WT0s; }
  else if (region == 1) { W = Wn0; WT = WT0n; }
  else if (region == 2) { W = Ws1; WT = WT1s; }
  else                  { W = Wn1; WT = WT1n; }
  if (region < 2) { k = local & 511;  n = local >> 9;  N = 512; }
  else            { k = local & 1023; n = local >> 10; N = 256; }
  WT[local] = f2bf(W[(size_t)k * N + n]);
}

__global__ void zero_out_kernel(float4* __restrict__ out) {
  out[blockIdx.x * 256 + threadIdx.x] = float4{0.f, 0.f, 0.f, 0.f};
}

// ---- Hall: rows<25600 from neigh1, else from nodes. 2 rows/block.
__global__ void gather_self_kernel(const float* __restrict__ x,
                                   const int* __restrict__ neigh1,
                                   const int* __restrict__ nodes,
                                   unsigned short* __restrict__ out) {
  int row = blockIdx.x * 2 + (threadIdx.x >> 7);
  int src = row < 25600 ? neigh1[row] : nodes[row - 25600];
  int c4 = (threadIdx.x & 127) << 2;
  const float4 v = *reinterpret_cast<const float4*>(x + (size_t)src * 512 + c4);
  ushort4 o; o.x = f2bf(v.x); o.y = f2bf(v.y); o.z = f2bf(v.z); o.w = f2bf(v.w);
  *reinterpret_cast<ushort4*>(out + (size_t)row * 512 + c4) = o;
}

// ---- out[row] = bf16(mean_{j<10} x[idx[row*10+j]]), the 524 MB kernel.
__global__ void gather_mean10_kernel(const float* __restrict__ x,
                                     const int* __restrict__ idx,
                                     unsigned short* __restrict__ out) {
  int row = blockIdx.x * 2 + (threadIdx.x >> 7);
  int c4 = (threadIdx.x & 127) << 2;
  float4 acc = {0.f, 0.f, 0.f, 0.f};
  const int* ip = idx + (size_t)row * 10;
  #pragma unroll
  for (int j = 0; j < 10; ++j) {
    const float4 v = *reinterpret_cast<const float4*>(x + (size_t)ip[j] * 512 + c4);
    acc.x += v.x; acc.y += v.y; acc.z += v.z; acc.w += v.w;
  }
  const float s = 0.1f;
  ushort4 o; o.x = f2bf(acc.x * s); o.y = f2bf(acc.y * s);
  o.z = f2bf(acc.z * s); o.w = f2bf(acc.w * s);
  *reinterpret_cast<ushort4*>(out + (size_t)row * 512 + c4) = o;
}

// ---- out[g] = bf16(mean_{j<25} in[g*25+j]), COLS bf16 per row.
template <int COLS>
__global__ void group_mean25_kernel(const unsigned short* __restrict__ in,
                                    unsigned short* __restrict__ out) {
  constexpr int TPG = COLS / 4;          // threads per group
  int g = blockIdx.x * (256 / TPG) + threadIdx.x / TPG;
  int c4 = (threadIdx.x % TPG) * 4;
  float a0 = 0, a1 = 0, a2 = 0, a3 = 0;
  for (int j = 0; j < 25; ++j) {
    ushort4 v = *reinterpret_cast<const ushort4*>(in + ((size_t)g * 25 + j) * COLS + c4);
    a0 += bf2f(v.x); a1 += bf2f(v.y); a2 += bf2f(v.z); a3 += bf2f(v.w);
  }
  const float s = 1.0f / 25.0f;
  ushort4 o; o.x = f2bf(a0 * s); o.y = f2bf(a1 * s); o.z = f2bf(a2 * s); o.w = f2bf(a3 * s);
  *reinterpret_cast<ushort4*>(out + (size_t)g * COLS + c4) = o;
}

// ---- NT GEMM core: 128x128 tile, BK=32, 4 waves 2x2, 16x16x32 bf16 MFMA.
template <bool RELU, bool OUTF32, bool ATOMIC>
DEVINL void gemm_core(const unsigned short* __restrict__ A, int lda,
                      const unsigned short* __restrict__ Bt, int ldb,
                      void* __restrict__ C, int ldc, int Kc,
                      long tm, long tn, long col0,
                      unsigned short* As, unsigned short* Bs) {
  const int t = threadIdx.x;
  const int w = t >> 6;
  const int l = t & 63;
  const int wm = w >> 1, wn = w & 1;
  f32x4 acc[4][4] = {};
  const int s_r = l >> 2;          // staged row within 16-row chunk
  const int s_kc = (l & 3) * 8;    // staged k-chunk (8 elems = 16 B)

  for (int kt = 0; kt < Kc; kt += 32) {
    __syncthreads();  // LDS free
    #pragma unroll
    for (int r = 0; r < 2; ++r) {
      const int chunk = r * 64 + w * 16;
      gload_lds16(A + (size_t)(tm + chunk + s_r) * lda + kt + s_kc, As + chunk * 32);
      gload_lds16(Bt + (size_t)(tn + chunk + s_r) * ldb + kt + s_kc, Bs + chunk * 32);
    }
    __syncthreads();  // staged (barrier drains vmcnt)

    bf16x8 af[4], bfr[4];
    const unsigned short* Ab = As + ((size_t)(wm * 64 + (l & 15)) * 32 + (l >> 4) * 8);
    const unsigned short* Bb = Bs + ((size_t)(wn * 64 + (l & 15)) * 32 + (l >> 4) * 8);
    #pragma unroll
    for (int f = 0; f < 4; ++f) {
      af[f] = *reinterpret_cast<const bf16x8*>(Ab + f * 16 * 32);
      bfr[f] = *reinterpret_cast<const bf16x8*>(Bb + f * 16 * 32);
    }
    #pragma unroll
    for (int i = 0; i < 4; ++i)
      #pragma unroll
      for (int j = 0; j < 4; ++j)
        acc[i][j] = __builtin_amdgcn_mfma_f32_16x16x32_bf16(af[i], bfr[j], acc[i][j], 0, 0, 0);
  }

  // epilogue: C/D layout col = l&15, row = (l>>4)*4 + r
  #pragma unroll
  for (int i = 0; i < 4; ++i) {
    #pragma unroll
    for (int j = 0; j < 4; ++j) {
      #pragma unroll
      for (int r = 0; r < 4; ++r) {
        float v = acc[i][j][r];
        if (RELU) v = fmaxf(v, 0.0f);
        const long row = tm + wm * 64 + i * 16 + (l >> 4) * 4 + r;
        const long col = col0 + tn + wn * 64 + j * 16 + (l & 15);
        if (OUTF32) {
          if (ATOMIC) atomicAdd((float*)C + row * ldc + col, v);
          else        ((float*)C)[row * ldc + col] = v;
        } else {
          ((unsigned short*)C)[row * ldc + col] = f2bf(v);
        }
      }
    }
  }
}

// layer 0, one launch: grid (8, 208). bx<4 -> self half (Ws0, cols 0-511),
// bx>=4 -> neighbor half (Wn0, cols 512-1023).
__global__ __launch_bounds__(256) void gemm0_kernel(
    const unsigned short* __restrict__ Hall, const unsigned short* __restrict__ Hmall,
    const unsigned short* __restrict__ WT0s, const unsigned short* __restrict__ WT0n,
    unsigned short* __restrict__ C1all) {
  __shared__ __align__(16) unsigned short As[128 * 32];
  __shared__ __align__(16) unsigned short Bs[128 * 32];
  const int half = blockIdx.x >> 2;
  const long tn = (long)(blockIdx.x & 3) * 128;
  const long tm = (long)blockIdx.y * 128;
  gemm_core<true, false, false>(half ? Hmall : Hall, 512,
                                half ? WT0n : WT0s, 512,
                                C1all, 1024, 512, tm, tn, half ? 512 : 0, As, Bs);
}

// layer 1, split-K + dual-pass via z: grid (2, 8, 8). z>>2 = pass, z&3 = k-quarter.
__global__ __launch_bounds__(256) void gemm1_kernel(
    const unsigned short* __restrict__ C0, const unsigned short* __restrict__ WT1s,
    const unsigned short* __restrict__ M1, const unsigned short* __restrict__ WT1n,
    float* __restrict__ out) {
  __shared__ __align__(16) unsigned short As[128 * 32];
  __shared__ __align__(16) unsigned short Bs[128 * 32];
  const int pass = blockIdx.z >> 2;
  const int k0 = (blockIdx.z & 3) * 256;
  gemm_core<false, true, true>((pass ? M1 : C0) + k0, 1024,
                               (pass ? WT1n : WT1s) + k0, 1024,
                               out, 256, 256,
                               (long)blockIdx.y * 128, (long)blockIdx.x * 128, 0, As, Bs);
}

extern "C" void kernel_launch(void* const* d_in, const int* in_sizes, int n_in,
                              void* d_out, int out_size, void* d_ws, size_t ws_size,
                              hipStream_t stream) {
  const float* x      = (const float*)d_in[0];   // [200000, 512]
  const int*   nodes  = (const int*)d_in[1];     // [1024]
  const int*   neigh1 = (const int*)d_in[2];     // [25600]
  const int*   neigh2 = (const int*)d_in[3];     // [256000]
  const float* Ws0    = (const float*)d_in[4];   // [512, 512]
  const float* Wn0    = (const float*)d_in[5];   // [512, 512]
  const float* Ws1    = (const float*)d_in[6];   // [1024, 256]
  const float* Wn1    = (const float*)d_in[7];   // [1024, 256]
  float* out = (float*)d_out;                    // [1024, 256]

  char* p = (char*)d_ws;
  unsigned short* WT0s  = (unsigned short*)p; p += (size_t)512 * 512 * 2;
  unsigned short* WT0n  = (unsigned short*)p; p += (size_t)512 * 512 * 2;
  unsigned short* WT1s  = (unsigned short*)p; p += (size_t)256 * 1024 * 2;
  unsigned short* WT1n  = (unsigned short*)p; p += (size_t)256 * 1024 * 2;
  unsigned short* Hall  = (unsigned short*)p; p += (size_t)26624 * 512 * 2;
  unsigned short* Hmall = (unsigned short*)p; p += (size_t)26624 * 512 * 2;
  unsigned short* C1all = (unsigned short*)p; p += (size_t)26624 * 1024 * 2;
  unsigned short* M1    = (unsigned short*)p; p += (size_t)1024 * 1024 * 2;

  unsigned short* H0m = Hmall + (size_t)25600 * 512;           // rows 25600+
  const unsigned short* C0 = C1all + (size_t)25600 * 1024;     // rows 25600+

  // 1. weights -> bf16 [N][K]; zero the f32 output (layer-1 uses atomics)
  hipLaunchKernelGGL(weights_cast_kernel, dim3(4096), dim3(256), 0, stream,
                     Ws0, Wn0, Ws1, Wn1, WT0s, WT0n, WT1s, WT1n);
  hipLaunchKernelGGL(zero_out_kernel, dim3(256), dim3(256), 0, stream, (float4*)out);

  // 2. gathers / means
  hipLaunchKernelGGL(gather_self_kernel, dim3(13312), dim3(256), 0, stream, x, neigh1, nodes, Hall);
  hipLaunchKernelGGL(gather_mean10_kernel, dim3(12800), dim3(256), 0, stream, x, neigh2, Hmall);
  hipLaunchKernelGGL(group_mean25_kernel<512>, dim3(512), dim3(256), 0, stream, Hall, H0m);

  // 3. layer 0: C1all = relu([Hall@Ws0 | Hmall@Wn0])
  hipLaunchKernelGGL(gemm0_kernel, dim3(8, 208), dim3(256), 0, stream,
                     Hall, Hmall, WT0s, WT0n, C1all);

  // 4. M1 = mean25(C1all top)
  hipLaunchKernelGGL(group_mean25_kernel<1024>, dim3(1024), dim3(256), 0, stream, C1all, M1);

  // 5. out += C0@Ws1 ; out += M1@Wn1  (split-K, f32 atomics)
  hipLaunchKernelGGL(gemm1_kernel, dim3(2, 8, 8), dim3(256), 0, stream,
                     C0, WT1s, M1, WT1n, out);
}